// Round 1
// baseline (786.459 us; speedup 1.0000x reference)
//
#include <hip/hip_runtime.h>
#include <hip/hip_bf16.h>

#define TT 512
#define BB 4096

// tanh(x) = 1 - 2/(exp(2x)+1); v_exp_f32 + v_rcp_f32, ~1e-6 abs error, correct
// saturation at +-inf.
__device__ __forceinline__ float fast_tanh(float x){
  float e = __builtin_amdgcn_exp2f(x * 2.885390081777927f);  // 2*log2(e)
  float r = __builtin_amdgcn_rcpf(e + 1.0f);
  return fmaf(-2.0f, r, 1.0f);
}
__device__ __forceinline__ float bflo(unsigned u){ return __uint_as_float(u << 16); }
__device__ __forceinline__ float bfhi(unsigned u){ return __uint_as_float(u & 0xffff0000u); }

// Layer 0: reads x [B][6][T] f32, writes bf16 planes out0/out1 = [T][B][8].
// 8 lanes per (b,dir): lane i owns h_i. Wave = 4 b's x 2 dirs (fwd lanes 0-31).
__global__ __launch_bounds__(256) void rnn_l0(
    const float* __restrict__ x,
    const float* __restrict__ Wih, const float* __restrict__ Whh,
    const float* __restrict__ bih, const float* __restrict__ bhh,
    __hip_bfloat16* __restrict__ out0, __hip_bfloat16* __restrict__ out1)
{
  const int tid  = blockIdx.x*256 + threadIdx.x;
  const int lane = tid & 63;
  const int wave = tid >> 6;
  const int g = lane >> 3, i = lane & 7;
  const int dir = g >> 2;
  const int b   = wave*4 + (g & 3);
  const int sbase = (lane & 0x38) << 2;   // byte base for ds_bpermute within 8-lane group

  float wi[6], wh[8];
  #pragma unroll
  for (int c=0;c<6;c++) wi[c] = Wih[(dir*8+i)*6 + c];
  #pragma unroll
  for (int j=0;j<8;j++) wh[j] = Whh[(dir*8+i)*8 + j];
  const float bias = bih[dir*8+i] + bhh[dir*8+i];

  const float* xb = x + (size_t)b*6*TT;
  __hip_bfloat16* outp = (dir ? out1 : out0) + b*8 + i;
  const int dt = dir ? -1 : 1;
  int t = dir ? TT-1 : 0;

  float xc[6];
  #pragma unroll
  for (int c=0;c<6;c++) xc[c] = xb[c*TT + t];

  float h = 0.f;
  for (int s=0; s<TT; ++s){
    const int tl = (s==TT-1) ? t : t+dt;
    float xn[6];                       // prefetch next step's inputs
    #pragma unroll
    for (int c=0;c<6;c++) xn[c] = xb[c*TT + tl];
    float a0=bias, a1=0.f;
    a0=fmaf(wi[0],xc[0],a0); a1=fmaf(wi[1],xc[1],a1);
    a0=fmaf(wi[2],xc[2],a0); a1=fmaf(wi[3],xc[3],a1);
    a0=fmaf(wi[4],xc[4],a0); a1=fmaf(wi[5],xc[5],a1);
    float r0=0.f, r1=0.f;
    #pragma unroll
    for (int j=0;j<8;j+=2){
      float hj0 = __int_as_float(__builtin_amdgcn_ds_bpermute(sbase + 4*j,     __float_as_int(h)));
      float hj1 = __int_as_float(__builtin_amdgcn_ds_bpermute(sbase + 4*(j+1), __float_as_int(h)));
      r0 = fmaf(wh[j],   hj0, r0);
      r1 = fmaf(wh[j+1], hj1, r1);
    }
    h = fast_tanh((a0+a1) + (r0+r1));
    outp[(size_t)t*(BB*8)] = __float2bfloat16(h);
    t = tl;
    #pragma unroll
    for (int c=0;c<6;c++) xc[c] = xn[c];
  }
}

// Layers 1..3: reads bf16 planes in0/in1 ([T][B][8] each; features 0-7 fwd, 8-15 bwd),
// writes planes (LAST=0) or final fwd h to lastv[b*16+i] f32 (LAST=1, dir0 only).
template<int LAST>
__global__ __launch_bounds__(256) void rnn_lN(
    const __hip_bfloat16* __restrict__ in0, const __hip_bfloat16* __restrict__ in1,
    const float* __restrict__ Wih, const float* __restrict__ Whh,
    const float* __restrict__ bih, const float* __restrict__ bhh,
    __hip_bfloat16* __restrict__ out0, __hip_bfloat16* __restrict__ out1,
    float* __restrict__ lastv)
{
  const int tid  = blockIdx.x*256 + threadIdx.x;
  const int lane = tid & 63;
  const int wave = tid >> 6;
  const int g = lane >> 3, i = lane & 7;
  const int dir = LAST ? 0 : (g >> 2);
  const int b   = LAST ? (wave*8 + g) : (wave*4 + (g & 3));
  const int sbase = (lane & 0x38) << 2;

  float wi[16], wh[8];
  #pragma unroll
  for (int c=0;c<16;c++) wi[c] = Wih[(dir*8+i)*16 + c];
  #pragma unroll
  for (int j=0;j<8;j++) wh[j] = Whh[(dir*8+i)*8 + j];
  const float bias = bih[dir*8+i] + bhh[dir*8+i];

  const uint4* p0 = (const uint4*)in0 + b;   // one uint4 = 8 bf16 = one (t,b) row
  const uint4* p1 = (const uint4*)in1 + b;
  __hip_bfloat16* outp = LAST ? nullptr : ((dir ? out1 : out0) + b*8 + i);
  const int dt = dir ? -1 : 1;
  int t = dir ? TT-1 : 0;

  uint4 va = p0[(size_t)t*BB];
  uint4 vb = p1[(size_t)t*BB];
  float h = 0.f;
  for (int s=0; s<TT; ++s){
    const int tl = (s==TT-1) ? t : t+dt;
    uint4 na = p0[(size_t)tl*BB];            // prefetch next step
    uint4 nb = p1[(size_t)tl*BB];
    float a0=bias, a1=0.f, a2=0.f, a3=0.f;
    a0=fmaf(wi[0], bflo(va.x),a0); a1=fmaf(wi[1], bfhi(va.x),a1);
    a2=fmaf(wi[2], bflo(va.y),a2); a3=fmaf(wi[3], bfhi(va.y),a3);
    a0=fmaf(wi[4], bflo(va.z),a0); a1=fmaf(wi[5], bfhi(va.z),a1);
    a2=fmaf(wi[6], bflo(va.w),a2); a3=fmaf(wi[7], bfhi(va.w),a3);
    a0=fmaf(wi[8], bflo(vb.x),a0); a1=fmaf(wi[9], bfhi(vb.x),a1);
    a2=fmaf(wi[10],bflo(vb.y),a2); a3=fmaf(wi[11],bfhi(vb.y),a3);
    a0=fmaf(wi[12],bflo(vb.z),a0); a1=fmaf(wi[13],bfhi(vb.z),a1);
    a2=fmaf(wi[14],bflo(vb.w),a2); a3=fmaf(wi[15],bfhi(vb.w),a3);
    float r0=0.f, r1=0.f;
    #pragma unroll
    for (int j=0;j<8;j+=2){
      float hj0 = __int_as_float(__builtin_amdgcn_ds_bpermute(sbase + 4*j,     __float_as_int(h)));
      float hj1 = __int_as_float(__builtin_amdgcn_ds_bpermute(sbase + 4*(j+1), __float_as_int(h)));
      r0 = fmaf(wh[j],   hj0, r0);
      r1 = fmaf(wh[j+1], hj1, r1);
    }
    h = fast_tanh(((a0+a1)+(a2+a3)) + (r0+r1));
    if (!LAST) outp[(size_t)t*(BB*8)] = __float2bfloat16(h);
    va = na; vb = nb; t = tl;
  }
  if (LAST) lastv[b*16 + i] = h;
}

// FC + layer-3 bwd (its value at t=T-1 is just the first step of the reversed
// scan with h0=0 -> tanh(proj(in[T-1]))). One thread per batch element.
__global__ __launch_bounds__(256) void fc_k(
    const __hip_bfloat16* __restrict__ in0, const __hip_bfloat16* __restrict__ in1,
    const float* __restrict__ Wih3, const float* __restrict__ bih3, const float* __restrict__ bhh3,
    const float* __restrict__ lastv,
    const float* __restrict__ fcw, const float* __restrict__ fcb,
    float* __restrict__ outp)
{
  const int b = blockIdx.x*256 + threadIdx.x;
  uint4 va = *((const uint4*)in0 + (size_t)(TT-1)*BB + b);
  uint4 vb = *((const uint4*)in1 + (size_t)(TT-1)*BB + b);
  float inv[16];
  inv[0]=bflo(va.x);  inv[1]=bfhi(va.x);  inv[2]=bflo(va.y);  inv[3]=bfhi(va.y);
  inv[4]=bflo(va.z);  inv[5]=bfhi(va.z);  inv[6]=bflo(va.w);  inv[7]=bfhi(va.w);
  inv[8]=bflo(vb.x);  inv[9]=bfhi(vb.x);  inv[10]=bflo(vb.y); inv[11]=bfhi(vb.y);
  inv[12]=bflo(vb.z); inv[13]=bfhi(vb.z); inv[14]=bflo(vb.w); inv[15]=bfhi(vb.w);
  float lv[16];
  #pragma unroll
  for (int k=0;k<8;k++) lv[k] = lastv[b*16+k];
  #pragma unroll
  for (int ii=0; ii<8; ++ii){
    float a = bih3[8+ii] + bhh3[8+ii];     // dir=1 rows
    #pragma unroll
    for (int j=0;j<16;j++) a = fmaf(Wih3[(8+ii)*16 + j], inv[j], a);
    lv[8+ii] = fast_tanh(a);
  }
  #pragma unroll
  for (int c=0;c<2;c++){
    float o = fcb[c];
    #pragma unroll
    for (int k=0;k<16;k++) o = fmaf(fcw[c*16+k], lv[k], o);
    outp[b*2+c] = o;
  }
}

extern "C" void kernel_launch(void* const* d_in, const int* in_sizes, int n_in,
                              void* d_out, int out_size, void* d_ws, size_t ws_size,
                              hipStream_t stream)
{
  const float* x    = (const float*)d_in[0];
  const float* Wih0 = (const float*)d_in[1];
  const float* Whh0 = (const float*)d_in[2];
  const float* bih0 = (const float*)d_in[3];
  const float* bhh0 = (const float*)d_in[4];
  const float* Wih  = (const float*)d_in[5];   // [3][2][8][16]
  const float* Whh  = (const float*)d_in[6];   // [3][2][8][8]
  const float* bih  = (const float*)d_in[7];   // [3][2][8]
  const float* bhh  = (const float*)d_in[8];
  const float* fcw  = (const float*)d_in[9];   // [2][16]
  const float* fcb  = (const float*)d_in[10];

  const size_t PLANE = (size_t)TT*BB*8;        // elements per direction plane
  __hip_bfloat16* A0 = (__hip_bfloat16*)d_ws;
  __hip_bfloat16* A1 = A0 + PLANE;
  __hip_bfloat16* B0 = A1 + PLANE;
  __hip_bfloat16* B1 = B0 + PLANE;
  float* lastv = (float*)(B1 + PLANE);         // [B][16] f32, only 0..7 used
  if (ws_size < PLANE*4*sizeof(__hip_bfloat16) + (size_t)BB*16*sizeof(float)) return;

  // layer 0: x -> A
  rnn_l0<<<256,256,0,stream>>>(x, Wih0, Whh0, bih0, bhh0, A0, A1);
  // layer 1: A -> B
  rnn_lN<0><<<256,256,0,stream>>>(A0,A1, Wih,     Whh,     bih,    bhh,    B0,B1, nullptr);
  // layer 2: B -> A
  rnn_lN<0><<<256,256,0,stream>>>(B0,B1, Wih+256, Whh+128, bih+16, bhh+16, A0,A1, nullptr);
  // layer 3 fwd only: A -> lastv[b][0:8]
  rnn_lN<1><<<128,256,0,stream>>>(A0,A1, Wih+512, Whh+256, bih+32, bhh+32, nullptr,nullptr, lastv);
  // layer 3 bwd (single step) + FC
  fc_k<<<16,256,0,stream>>>(A0,A1, Wih+512, bih+32, bhh+32, lastv, fcw, fcb, (float*)d_out);
}

// Round 2
// 411.620 us; speedup vs baseline: 1.9106x; 1.9106x over previous
//
#include <hip/hip_runtime.h>
#include <hip/hip_bf16.h>

#define TT 512
#define BB 4096
#define PF 8   // prefetch depth (steps of input held in registers)

// tanh(x) = 1 - 2/(exp(2x)+1); v_exp_f32 + v_rcp_f32, ~1e-6 abs error.
__device__ __forceinline__ float fast_tanh(float x){
  float e = __builtin_amdgcn_exp2f(x * 2.885390081777927f);  // 2*log2(e)
  float r = __builtin_amdgcn_rcpf(e + 1.0f);
  return fmaf(-2.0f, r, 1.0f);
}
__device__ __forceinline__ float bflo(unsigned u){ return __uint_as_float(u << 16); }
__device__ __forceinline__ float bfhi(unsigned u){ return __uint_as_float(u & 0xffff0000u); }

// DPP quad_perm broadcast of slot J within each 4-lane quad (VALU, ~4cy latency).
template<int J>
__device__ __forceinline__ float qpb(float v){
  return __int_as_float(__builtin_amdgcn_mov_dpp(__float_as_int(v), J*0x55, 0xF, 0xF, true));
}
// ds_swizzle xor-4: exchange h between the two quads of each 8-lane group.
__device__ __forceinline__ float swap4(float v){
  return __int_as_float(__builtin_amdgcn_ds_swizzle(__float_as_int(v), 0x101F));
}

// One recurrence step: h_new = tanh(at + Whh_row . h_group).
// whq = weights for own-quad h slots, whs = for other-quad slots (pre-permuted).
__device__ __forceinline__ float rstep(float h, float at,
                                       const float* whq, const float* whs){
  float hs = swap4(h);               // other quad's h (DS pipe, overlaps DPP chain)
  float r0 = at, r1 = 0.f;
  r0 = fmaf(whq[0], qpb<0>(h), r0);
  r1 = fmaf(whq[1], qpb<1>(h), r1);
  r0 = fmaf(whq[2], qpb<2>(h), r0);
  r1 = fmaf(whq[3], qpb<3>(h), r1);
  r0 = fmaf(whs[0], qpb<0>(hs), r0);
  r1 = fmaf(whs[1], qpb<1>(hs), r1);
  r0 = fmaf(whs[2], qpb<2>(hs), r0);
  r1 = fmaf(whs[3], qpb<3>(hs), r1);
  return fast_tanh(r0 + r1);
}

// Layer 0: reads x [B][6][T] f32, writes bf16 planes out0/out1 = [T][B][8].
// 8 lanes per (b,dir): lane i owns h_i. Wave = 4 b's x 2 dirs.
__global__ __launch_bounds__(256) void rnn_l0(
    const float* __restrict__ x,
    const float* __restrict__ Wih, const float* __restrict__ Whh,
    const float* __restrict__ bih, const float* __restrict__ bhh,
    __hip_bfloat16* __restrict__ out0, __hip_bfloat16* __restrict__ out1)
{
  const int tid  = blockIdx.x*256 + threadIdx.x;
  const int lane = tid & 63;
  const int wave = tid >> 6;
  const int g = lane >> 3, i = lane & 7;
  const int dir = g >> 2;
  const int b   = wave*4 + (g & 3);
  const int qp  = (lane >> 2) & 1;      // quad parity within 8-lane group

  float wi[6], whq[4], whs[4];
  #pragma unroll
  for (int c=0;c<6;c++) wi[c] = Wih[(dir*8+i)*6 + c];
  #pragma unroll
  for (int j=0;j<4;j++){
    whq[j] = Whh[(dir*8+i)*8 + qp*4 + j];
    whs[j] = Whh[(dir*8+i)*8 + (1-qp)*4 + j];
  }
  const float bias = bih[dir*8+i] + bhh[dir*8+i];

  const float* xb = x + (size_t)b*6*TT;
  __hip_bfloat16* outp = (dir ? out1 : out0) + b*8 + i;

  float bufX[PF][6];
  #pragma unroll
  for (int k=0;k<PF;k++){
    const int tq = dir ? (TT-1-k) : k;
    #pragma unroll
    for (int c=0;c<6;c++) bufX[k][c] = xb[c*TT + tq];
  }

  float h = 0.f;
  #pragma unroll 1
  for (int s=0; s<TT; s+=PF){
    #pragma unroll
    for (int k=0;k<PF;k++){
      const int step = s+k;
      const int t = dir ? (TT-1-step) : step;
      float xc[6];
      #pragma unroll
      for (int c=0;c<6;c++) xc[c] = bufX[k][c];
      const int ns = step + PF;
      if (ns < TT){                          // wave-uniform
        const int tn = dir ? (TT-1-ns) : ns;
        #pragma unroll
        for (int c=0;c<6;c++) bufX[k][c] = xb[c*TT + tn];
      }
      float a0=bias, a1=0.f;
      a0=fmaf(wi[0],xc[0],a0); a1=fmaf(wi[1],xc[1],a1);
      a0=fmaf(wi[2],xc[2],a0); a1=fmaf(wi[3],xc[3],a1);
      a0=fmaf(wi[4],xc[4],a0); a1=fmaf(wi[5],xc[5],a1);
      h = rstep(h, a0+a1, whq, whs);
      outp[(size_t)t*(BB*8)] = __float2bfloat16(h);
    }
  }
}

// Layers 1..3: reads bf16 planes in0/in1 ([T][B][8] each), writes planes
// (LAST=0) or final fwd h to lastv[b*16+i] f32 (LAST=1, dir0 only).
template<int LAST>
__global__ __launch_bounds__(256) void rnn_lN(
    const __hip_bfloat16* __restrict__ in0, const __hip_bfloat16* __restrict__ in1,
    const float* __restrict__ Wih, const float* __restrict__ Whh,
    const float* __restrict__ bih, const float* __restrict__ bhh,
    __hip_bfloat16* __restrict__ out0, __hip_bfloat16* __restrict__ out1,
    float* __restrict__ lastv)
{
  const int tid  = blockIdx.x*256 + threadIdx.x;
  const int lane = tid & 63;
  const int wave = tid >> 6;
  const int g = lane >> 3, i = lane & 7;
  const int dir = LAST ? 0 : (g >> 2);
  const int b   = LAST ? (wave*8 + g) : (wave*4 + (g & 3));
  const int qp  = (lane >> 2) & 1;

  float wi[16], whq[4], whs[4];
  #pragma unroll
  for (int c=0;c<16;c++) wi[c] = Wih[(dir*8+i)*16 + c];
  #pragma unroll
  for (int j=0;j<4;j++){
    whq[j] = Whh[(dir*8+i)*8 + qp*4 + j];
    whs[j] = Whh[(dir*8+i)*8 + (1-qp)*4 + j];
  }
  const float bias = bih[dir*8+i] + bhh[dir*8+i];

  const uint4* p0 = (const uint4*)in0 + b;   // one uint4 = 8 bf16 = one (t,b) row
  const uint4* p1 = (const uint4*)in1 + b;
  __hip_bfloat16* outp = LAST ? nullptr : ((dir ? out1 : out0) + b*8 + i);

  uint4 bufA[PF], bufB[PF];
  #pragma unroll
  for (int k=0;k<PF;k++){
    const int tq = dir ? (TT-1-k) : k;
    bufA[k] = p0[(size_t)tq*BB];
    bufB[k] = p1[(size_t)tq*BB];
  }

  float h = 0.f;
  #pragma unroll 1
  for (int s=0; s<TT; s+=PF){
    #pragma unroll
    for (int k=0;k<PF;k++){
      const int step = s+k;
      const int t = dir ? (TT-1-step) : step;
      const uint4 va = bufA[k], vb = bufB[k];
      const int ns = step + PF;
      if (ns < TT){                          // wave-uniform
        const int tn = dir ? (TT-1-ns) : ns;
        bufA[k] = p0[(size_t)tn*BB];
        bufB[k] = p1[(size_t)tn*BB];
      }
      float a0=bias, a1=0.f, a2=0.f, a3=0.f;
      a0=fmaf(wi[0], bflo(va.x),a0); a1=fmaf(wi[1], bfhi(va.x),a1);
      a2=fmaf(wi[2], bflo(va.y),a2); a3=fmaf(wi[3], bfhi(va.y),a3);
      a0=fmaf(wi[4], bflo(va.z),a0); a1=fmaf(wi[5], bfhi(va.z),a1);
      a2=fmaf(wi[6], bflo(va.w),a2); a3=fmaf(wi[7], bfhi(va.w),a3);
      a0=fmaf(wi[8], bflo(vb.x),a0); a1=fmaf(wi[9], bfhi(vb.x),a1);
      a2=fmaf(wi[10],bflo(vb.y),a2); a3=fmaf(wi[11],bfhi(vb.y),a3);
      a0=fmaf(wi[12],bflo(vb.z),a0); a1=fmaf(wi[13],bfhi(vb.z),a1);
      a2=fmaf(wi[14],bflo(vb.w),a2); a3=fmaf(wi[15],bfhi(vb.w),a3);
      h = rstep(h, (a0+a1)+(a2+a3), whq, whs);
      if (!LAST) outp[(size_t)t*(BB*8)] = __float2bfloat16(h);
    }
  }
  if (LAST) lastv[b*16 + i] = h;
}

// FC + layer-3 bwd at t=T-1 (first step of reversed scan with h0=0 ->
// tanh(proj(in[T-1]))). One thread per batch element.
__global__ __launch_bounds__(256) void fc_k(
    const __hip_bfloat16* __restrict__ in0, const __hip_bfloat16* __restrict__ in1,
    const float* __restrict__ Wih3, const float* __restrict__ bih3, const float* __restrict__ bhh3,
    const float* __restrict__ lastv,
    const float* __restrict__ fcw, const float* __restrict__ fcb,
    float* __restrict__ outp)
{
  const int b = blockIdx.x*256 + threadIdx.x;
  uint4 va = *((const uint4*)in0 + (size_t)(TT-1)*BB + b);
  uint4 vb = *((const uint4*)in1 + (size_t)(TT-1)*BB + b);
  float inv[16];
  inv[0]=bflo(va.x);  inv[1]=bfhi(va.x);  inv[2]=bflo(va.y);  inv[3]=bfhi(va.y);
  inv[4]=bflo(va.z);  inv[5]=bfhi(va.z);  inv[6]=bflo(va.w);  inv[7]=bfhi(va.w);
  inv[8]=bflo(vb.x);  inv[9]=bfhi(vb.x);  inv[10]=bflo(vb.y); inv[11]=bfhi(vb.y);
  inv[12]=bflo(vb.z); inv[13]=bfhi(vb.z); inv[14]=bflo(vb.w); inv[15]=bfhi(vb.w);
  float lv[16];
  #pragma unroll
  for (int k=0;k<8;k++) lv[k] = lastv[b*16+k];
  #pragma unroll
  for (int ii=0; ii<8; ++ii){
    float a = bih3[8+ii] + bhh3[8+ii];     // dir=1 rows
    #pragma unroll
    for (int j=0;j<16;j++) a = fmaf(Wih3[(8+ii)*16 + j], inv[j], a);
    lv[8+ii] = fast_tanh(a);
  }
  #pragma unroll
  for (int c=0;c<2;c++){
    float o = fcb[c];
    #pragma unroll
    for (int k=0;k<16;k++) o = fmaf(fcw[c*16+k], lv[k], o);
    outp[b*2+c] = o;
  }
}

extern "C" void kernel_launch(void* const* d_in, const int* in_sizes, int n_in,
                              void* d_out, int out_size, void* d_ws, size_t ws_size,
                              hipStream_t stream)
{
  const float* x    = (const float*)d_in[0];
  const float* Wih0 = (const float*)d_in[1];
  const float* Whh0 = (const float*)d_in[2];
  const float* bih0 = (const float*)d_in[3];
  const float* bhh0 = (const float*)d_in[4];
  const float* Wih  = (const float*)d_in[5];   // [3][2][8][16]
  const float* Whh  = (const float*)d_in[6];   // [3][2][8][8]
  const float* bih  = (const float*)d_in[7];   // [3][2][8]
  const float* bhh  = (const float*)d_in[8];
  const float* fcw  = (const float*)d_in[9];   // [2][16]
  const float* fcb  = (const float*)d_in[10];

  const size_t PLANE = (size_t)TT*BB*8;        // elements per direction plane
  __hip_bfloat16* A0 = (__hip_bfloat16*)d_ws;
  __hip_bfloat16* A1 = A0 + PLANE;
  __hip_bfloat16* B0 = A1 + PLANE;
  __hip_bfloat16* B1 = B0 + PLANE;
  float* lastv = (float*)(B1 + PLANE);         // [B][16] f32, only 0..7 used
  if (ws_size < PLANE*4*sizeof(__hip_bfloat16) + (size_t)BB*16*sizeof(float)) return;

  rnn_l0<<<256,256,0,stream>>>(x, Wih0, Whh0, bih0, bhh0, A0, A1);
  rnn_lN<0><<<256,256,0,stream>>>(A0,A1, Wih,     Whh,     bih,    bhh,    B0,B1, nullptr);
  rnn_lN<0><<<256,256,0,stream>>>(B0,B1, Wih+256, Whh+128, bih+16, bhh+16, A0,A1, nullptr);
  rnn_lN<1><<<128,256,0,stream>>>(A0,A1, Wih+512, Whh+256, bih+32, bhh+32, nullptr,nullptr, lastv);
  fc_k<<<16,256,0,stream>>>(A0,A1, Wih+512, bih+32, bhh+32, lastv, fcw, fcb, (float*)d_out);
}